// Round 11
// baseline (273.279 us; speedup 1.0000x reference)
//
#include <hip/hip_runtime.h>
#include <math.h>

// ---- problem constants ----
constexpr int Bc = 4, Lc = 2048, Kc = 30;
constexpr int Nn = Bc * Lc;            // 8192 nodes
constexpr int NSc = 1024, NVc = 256;
constexpr int NEc = Nn * Kc;           // 245760 edges
constexpr int SK = 263;                // 7 + 256 scalar GVP input dim
constexpr int KP = 288;                // K padded to 9x32 for MFMA

// ---- d_out float offsets (outputs concatenated flat in return order) ----
constexpr size_t OUT_NS = 0;                                  // (8192,1024)
constexpr size_t OUT_NV = (size_t)Nn * NSc;                   // (8192,256,3)
constexpr size_t OUT_ES = OUT_NV + (size_t)Nn * NVc * 3;      // (245760,32)
constexpr size_t OUT_EV = OUT_ES + (size_t)NEc * 32;          // (245760,1,3)
constexpr size_t OUT_EI = OUT_EV + (size_t)NEc * 3;           // (2,245760) as float

// ---- workspace float offsets ----
constexpr size_t WS_SIN = 0;                                  // (8192,263) s_in
constexpr size_t WS_NDV = WS_SIN + (size_t)Nn * SK;           // (8192,9) node_v
constexpr size_t WS_EIX = WS_NDV + (size_t)Nn * 9;            // (245760) int E_idx
constexpr size_t WS_EDS = WS_EIX + (size_t)NEc;               // (245760) E_dist
constexpr size_t WS_CMF = WS_EDS + (size_t)NEc;               // (8192) canonical coord_mask float

using short8 = __attribute__((ext_vector_type(8))) short;   // 8 bf16 (4 VGPRs)
using f32x4  = __attribute__((ext_vector_type(4))) float;   // 4 fp32 acc

__device__ __forceinline__ void norml3(float& x, float& y, float& z) {
  float ss = x*x + y*y + z*z;
  float inv = 1.0f / sqrtf(ss + 1e-8f);
  x *= inv; y *= inv; z *= inv;
}

// RNE split x = hi + lo (both exactly representable in bf16)
__device__ __forceinline__ void bf16split(float x, unsigned short& h, unsigned short& l) {
  unsigned u = __float_as_uint(x);
  unsigned hb = (u + 0x7FFFu + ((u >> 16) & 1u)) & 0xFFFF0000u;
  float lf = x - __uint_as_float(hb);
  unsigned ul = __float_as_uint(lf);
  h = (unsigned short)(hb >> 16);
  l = (unsigned short)((ul + 0x7FFFu + ((ul >> 16) & 1u)) >> 16);
}

// ---------------- Kernel I: merged kmask (blocks 0..31) + kwhwv (blocks 32..35) ----
__global__ __launch_bounds__(256) void kinit(const unsigned char* __restrict__ cm,
                                             const float* __restrict__ coords,
                                             const int* __restrict__ resid,
                                             const unsigned char* __restrict__ pmask,
                                             const float* __restrict__ wh,
                                             const float* __restrict__ wv,
                                             float* __restrict__ ws,
                                             float4* __restrict__ pack,
                                             float4* __restrict__ whwv4,
                                             float4* __restrict__ wht4) {
  __shared__ float r0[256], r1[256], r2[256];
  __shared__ int flag;
  int tid = threadIdx.x;
  if (blockIdx.x < 32) {
    if (tid == 0) flag = 0;
    __syncthreads();
    int any = 0;
    for (int p = tid; p < 1024; p += 256)
      if (p & 3) any |= cm[p];
    if (any) atomicOr(&flag, 1);
    __syncthreads();
    bool bytefmt = (flag != 0);
    int n = blockIdx.x * 256 + tid;
    unsigned char v = bytefmt ? cm[n] : cm[4*n];  // LE low byte of int32 0/1
    ws[WS_CMF + n] = v ? 1.f : 0.f;
    int rm = (pmask[n] == 0) ? 1 : 0;
    int w = (resid[n] << 2) | ((v ? 1 : 0) << 1) | rm;
    float4 p;
    p.x = coords[(size_t)n*9 + 3];
    p.y = coords[(size_t)n*9 + 4];
    p.z = coords[(size_t)n*9 + 5];
    p.w = __int_as_float(w);
    pack[n] = p;
  } else {
    int lane = tid & 63, wid = tid >> 6;
    int vcol = (int)(blockIdx.x - 32) * 64 + lane;
    float a0 = 0.f, a1 = 0.f, a2 = 0.f;
    #pragma unroll 4
    for (int hh = 0; hh < 64; ++hh) {
      int h = wid * 64 + hh;
      float wvv = wv[(size_t)h * 256 + vcol];
      a0 = fmaf(wh[h],       wvv, a0);
      a1 = fmaf(wh[256 + h], wvv, a1);
      a2 = fmaf(wh[512 + h], wvv, a2);
    }
    r0[tid] = a0; r1[tid] = a1; r2[tid] = a2;
    __syncthreads();
    if (wid == 0) {
      a0 = r0[lane] + r0[lane+64] + r0[lane+128] + r0[lane+192];
      a1 = r1[lane] + r1[lane+64] + r1[lane+128] + r1[lane+192];
      a2 = r2[lane] + r2[lane+64] + r2[lane+128] + r2[lane+192];
      whwv4[vcol] = float4{a0, a1, a2, 0.f};
    } else if (wid == 1) {
      wht4[vcol] = float4{wh[vcol], wh[256 + vcol], wh[512 + vcol], 0.f};
    }
  }
}

// ---------------- Kernel A: per-node geometric features (64-thread blocks) --------
__global__ __launch_bounds__(64) void knode_geom(const float* __restrict__ coords,
                                                 float* __restrict__ ws) {
  int n = blockIdx.x * 64 + threadIdx.x;
  if (n >= Nn) return;
  int b = n / Lc, l = n % Lc;
  const float* Xb = coords + (size_t)b * Lc * 9;
  float ax[7][3];
  #pragma unroll
  for (int m = 0; m < 7; ++m) {
    int t = 3*l + m - 2;
    if (t >= 0 && t < 3*Lc) { ax[m][0]=Xb[t*3+0]; ax[m][1]=Xb[t*3+1]; ax[m][2]=Xb[t*3+2]; }
    else { ax[m][0]=0.f; ax[m][1]=0.f; ax[m][2]=0.f; }
  }
  float U[5][3];
  #pragma unroll
  for (int mi = 0; mi < 5; ++mi) {
    int t = 3*l - 1 + mi;
    if (t >= 0 && t <= 3*Lc - 2) {
      float x = ax[mi+2][0]-ax[mi+1][0], y = ax[mi+2][1]-ax[mi+1][1], z = ax[mi+2][2]-ax[mi+1][2];
      norml3(x,y,z);
      U[mi][0]=x; U[mi][1]=y; U[mi][2]=z;
    } else { U[mi][0]=0.f; U[mi][1]=0.f; U[mi][2]=0.f; }
  }
  float cph[3], sph[3];
  #pragma unroll
  for (int a = 0; a < 3; ++a) {
    int t = 3*l + a - 1;
    if (t < 0 || t > 3*Lc - 4) { cph[a] = 1.f; sph[a] = 0.f; continue; }
    const float *u2 = U[a], *u1 = U[a+1], *u0 = U[a+2];
    float n2x = u2[1]*u1[2]-u2[2]*u1[1], n2y = u2[2]*u1[0]-u2[0]*u1[2], n2z = u2[0]*u1[1]-u2[1]*u1[0];
    norml3(n2x,n2y,n2z);
    float n1x = u1[1]*u0[2]-u1[2]*u0[1], n1y = u1[2]*u0[0]-u1[0]*u0[2], n1z = u1[0]*u0[1]-u1[1]*u0[0];
    norml3(n1x,n1y,n1z);
    float cd = n2x*n1x + n2y*n1y + n2z*n1z;
    cd = fminf(fmaxf(cd, -1.f + 1e-7f), 1.f - 1e-7f);
    float dt = u2[0]*n1x + u2[1]*n1y + u2[2]*n1z;
    float sg = (dt > 0.f) ? 1.f : ((dt < 0.f) ? -1.f : 0.f);
    float D = sg * acosf(cd);
    cph[a] = cosf(D); sph[a] = sinf(D);
  }
  float fx=0.f,fy=0.f,fz=0.f, kx=0.f,ky=0.f,kz=0.f;
  if (l < Lc-1) { fx=ax[6][0]-ax[3][0]; fy=ax[6][1]-ax[3][1]; fz=ax[6][2]-ax[3][2]; norml3(fx,fy,fz); }
  if (l > 0)    { kx=ax[0][0]-ax[3][0]; ky=ax[0][1]-ax[3][1]; kz=ax[0][2]-ax[3][2]; norml3(kx,ky,kz); }
  float cx=ax[4][0]-ax[3][0], cy=ax[4][1]-ax[3][1], cz=ax[4][2]-ax[3][2]; norml3(cx,cy,cz);
  float nx=ax[2][0]-ax[3][0], ny=ax[2][1]-ax[3][1], nz=ax[2][2]-ax[3][2]; norml3(nx,ny,nz);
  float bix=cx+nx, biy=cy+ny, biz=cz+nz; norml3(bix,biy,biz);
  float px=cy*nz-cz*ny, py=cz*nx-cx*nz, pz=cx*ny-cy*nx; norml3(px,py,pz);
  const float c1 = 0.57735026f, c2 = 0.81649658f;
  float sx = -bix*c1 - px*c2, sy = -biy*c1 - py*c2, sz = -biz*c1 - pz*c2;

  float cmf = ws[WS_CMF + n];
  float* sr = ws + WS_SIN + (size_t)n * SK;
  sr[0]=cph[0]; sr[1]=cph[1]; sr[2]=cph[2]; sr[3]=sph[0]; sr[4]=sph[1]; sr[5]=sph[2]; sr[6]=cmf;
  float* vr = ws + WS_NDV + (size_t)n * 9;
  vr[0]=fx; vr[1]=fy; vr[2]=fz; vr[3]=kx; vr[4]=ky; vr[5]=kz; vr[6]=sx; vr[7]=sy; vr[8]=sz;
}

// ---------------- Kernel V: fused node vector path (dense float4 NV stores) -------
__global__ __launch_bounds__(256) void kvnode(const float4* __restrict__ wht4,
                                              const float4* __restrict__ whwv4,
                                              float* __restrict__ ws,
                                              float* __restrict__ out) {
  int tid = threadIdx.x, lane = tid & 63, wid = tid >> 6;
  int n = blockIdx.x * 4 + wid;
  const float* v = ws + WS_NDV + (size_t)n * 9;
  float v00=v[0],v01=v[1],v02=v[2];
  float v10=v[3],v11=v[4],v12=v[5];
  float v20=v[6],v21=v[7],v22=v[8];
  float p = 0.f;
  float vo[4][3];
  #pragma unroll
  for (int m = 0; m < 4; ++m) {
    int hv = lane + 64*m;
    float4 wt = wht4[hv];
    float vh0 = v00*wt.x + v10*wt.y + v20*wt.z;
    float vh1 = v01*wt.x + v11*wt.y + v21*wt.z;
    float vh2 = v02*wt.x + v12*wt.y + v22*wt.z;
    ws[WS_SIN + (size_t)n*SK + 7 + hv] = sqrtf(fmaxf(vh0*vh0 + vh1*vh1 + vh2*vh2, 1e-8f));
    int ho = lane*4 + m;
    float4 wc = whwv4[ho];
    float o0 = v00*wc.x + v10*wc.y + v20*wc.z;
    float o1 = v01*wc.x + v11*wc.y + v21*wc.z;
    float o2 = v02*wc.x + v12*wc.y + v22*wc.z;
    vo[m][0]=o0; vo[m][1]=o1; vo[m][2]=o2;
    p += fmaxf(o0*o0 + o1*o1 + o2*o2, 1e-8f);
  }
  #pragma unroll
  for (int off = 1; off < 64; off <<= 1) p += __shfl_xor(p, off);
  float isd = 1.f / sqrtf(p * (1.f/256.f));
  size_t o = OUT_NV + (size_t)n*768 + (size_t)lane*12;
  float4 f0 = {vo[0][0]*isd, vo[0][1]*isd, vo[0][2]*isd, vo[1][0]*isd};
  float4 f1 = {vo[1][1]*isd, vo[1][2]*isd, vo[2][0]*isd, vo[2][1]*isd};
  float4 f2 = {vo[2][2]*isd, vo[3][0]*isd, vo[3][1]*isd, vo[3][2]*isd};
  *(float4*)&out[o+0] = f0;
  *(float4*)&out[o+4] = f1;
  *(float4*)&out[o+8] = f2;
}

// ---------------- Kernel B: wave-autonomous exact top-30 threshold select --------
__global__ __launch_bounds__(256) void ktopk(const float4* __restrict__ pack,
                                             float* __restrict__ ws) {
  __shared__ unsigned long long cbuf[4][256];
  int tid = threadIdx.x, lane = tid & 63, wid = tid >> 6;
  int row = blockIdx.x * 4 + wid;
  int b = row >> 11;
  int i = row & (Lc - 1);
  const float4* P = pack + (size_t)b * Lc;
  int* eix = (int*)(ws + WS_EIX);
  unsigned long long lmask_lt = (1ULL << lane) - 1ULL;

  float4 pi = P[i];
  int wi = __float_as_int(pi.w);
  float cmi = ((wi >> 1) & 1) ? 1.f : 0.f;
  float rmi = (wi & 1) ? 1.f : 0.f;
  int ri = wi >> 2;

  unsigned a[32];
  unsigned lmin = 0xFFFFFFFFu;
  #pragma unroll
  for (int half = 0; half < 2; ++half) {
    float4 pjs[16];
    #pragma unroll
    for (int q = 0; q < 16; ++q)
      pjs[q] = P[lane + 64*(half*16 + q)];
    #pragma unroll
    for (int q = 0; q < 16; ++q) {
      int m = half*16 + q;
      int j = lane + 64*m;
      float4 pj = pjs[q];
      int wj = __float_as_int(pj.w);
      float cmj = ((wj >> 1) & 1) ? 1.f : 0.f;
      float rmj = (wj & 1) ? 1.f : 0.f;
      float dx = __fsub_rn(pi.x, pj.x);
      float dy = __fsub_rn(pi.y, pj.y);
      float dz = __fsub_rn(pi.z, pj.z);
      float ss = __fadd_rn(__fadd_rn(__fmul_rn(dx,dx), __fmul_rn(dy,dy)), __fmul_rn(dz,dz));
      float dist = __fsqrt_rn(__fadd_rn(ss, 1e-8f));
      float cm2 = __fmul_rn(cmi, cmj);
      float D = __fmul_rn(cm2, dist);
      int ad = ri - (wj >> 2); ad = ad < 0 ? -ad : ad;
      float covm = (ad <= 3) ? 0.f : 1.f;
      float dseq = (float)(i >= j ? i - j : j - i);
      float t1 = __fmul_rn(__fsub_rn(1.f, cm2), __fadd_rn(1e8f, __fmul_rn(dseq, 1e6f)));
      float rm2 = __fmul_rn(rmi, rmj);
      float t2 = __fmul_rn(__fsub_rn(1.f, rm2), 1e10f);
      float adj = __fadd_rn(__fadd_rn(__fmul_rn(D, covm), t1), t2);
      unsigned u = __float_as_uint(adj);   // adj >= 0 -> order-preserving bits
      a[m] = u;
      lmin = u < lmin ? u : lmin;
    }
  }

  // Tv = 30th-smallest lane-min. hi covers all possible adj (< 1.3e10 < 3.4e10).
  unsigned lo = 0u, hi = 0x51000000u;
  while (lo < hi) {
    unsigned mid = lo + ((hi - lo) >> 1);
    unsigned long long bal = __ballot(lmin <= mid);
    if (__popcll(bal) >= Kc) hi = mid; else lo = mid + 1u;
  }
  unsigned Tv = lo;

  // compact survivors into cbuf in (m, lane) order
  unsigned base = 0;
  #pragma unroll
  for (int m = 0; m < 32; ++m) {
    bool pred = (a[m] <= Tv);
    unsigned long long bal = __ballot(pred);
    if (pred) {
      unsigned pos = base + (unsigned)__popcll(bal & lmask_lt);
      if (pos < 256u)
        cbuf[wid][pos] = ((unsigned long long)a[m] << 32) | (unsigned)(lane + 64*m);
    }
    base += (unsigned)__popcll(bal);
  }
  unsigned M = base < 256u ? base : 256u;
  __builtin_amdgcn_wave_barrier();

  for (unsigned idx = (unsigned)lane; idx < M; idx += 64u) {
    unsigned long long k0 = cbuf[wid][idx];
    int rank = 0;
    for (unsigned t = 0; t < M; ++t) rank += (cbuf[wid][t] < k0) ? 1 : 0;
    if (rank < Kc) {
      int j = (int)(k0 & 2047ULL);
      float4 pj = P[j];
      int wj = __float_as_int(pj.w);
      float cmj = ((wj >> 1) & 1) ? 1.f : 0.f;
      float dx = __fsub_rn(pi.x, pj.x);
      float dy = __fsub_rn(pi.y, pj.y);
      float dz = __fsub_rn(pi.z, pj.z);
      float ss2 = __fadd_rn(__fadd_rn(__fmul_rn(dx,dx), __fmul_rn(dy,dy)), __fmul_rn(dz,dz));
      float dist = __fsqrt_rn(__fadd_rn(ss2, 1e-8f));
      float D = __fmul_rn(__fmul_rn(cmi, cmj), dist);
      eix[(size_t)row*Kc + rank] = j;
      ws[WS_EDS + (size_t)row*Kc + rank] = D;
    }
  }
}

// ---------------- Kernel P1: split s_in rows into bf16 hi/lo, K padded to 288 ------
__global__ __launch_bounds__(64) void kprepA(const float* __restrict__ ws,
                                             unsigned short* __restrict__ Ahi,
                                             unsigned short* __restrict__ Alo) {
  int n = blockIdx.x, t = threadIdx.x;
  const float* src = ws + WS_SIN + (size_t)n * SK;
  size_t dst = (size_t)n * KP;
  #pragma unroll
  for (int p = 0; p < 5; ++p) {
    int k = t + 64*p;
    if (k >= KP) break;
    float x = (k < SK) ? src[k] : 0.f;
    unsigned short h, l;
    bf16split(x, h, l);
    Ahi[dst + k] = h;
    Alo[dst + k] = l;
  }
}

// ---------------- Kernel P2: transpose weight -> bf16 hi/lo B^T[1024][288] ---------
__global__ __launch_bounds__(256) void kprepB(const float* __restrict__ wsw,
                                              unsigned short* __restrict__ Bhi,
                                              unsigned short* __restrict__ Blo) {
  __shared__ float tile[32][33];
  int bidx = blockIdx.x;           // 9 k-tiles x 32 c-tiles
  int kt = bidx % 9, ct = bidx / 9;
  int k0 = kt*32, c0 = ct*32;
  int t = threadIdx.x;
  int r = t >> 5, c = t & 31;
  #pragma unroll
  for (int p = 0; p < 4; ++p) {
    int k = k0 + r + 8*p;
    tile[r + 8*p][c] = (k < SK) ? wsw[(size_t)k*NSc + c0 + c] : 0.f;
  }
  __syncthreads();
  int cc = t >> 3, kq = (t & 7) * 4;
  ushort4 h4, l4;
  float x0 = tile[kq+0][cc], x1 = tile[kq+1][cc], x2 = tile[kq+2][cc], x3 = tile[kq+3][cc];
  bf16split(x0, h4.x, l4.x);
  bf16split(x1, h4.y, l4.y);
  bf16split(x2, h4.z, l4.z);
  bf16split(x3, h4.w, l4.w);
  size_t o = (size_t)(c0 + cc) * KP + k0 + kq;
  *(ushort4*)&Bhi[o] = h4;
  *(ushort4*)&Blo[o] = l4;
}

// ---------------- Kernel D2: S GEMM via MFMA, split-bf16 (3-term Markidis) --------
__global__ __launch_bounds__(256) void kgemm_s(const unsigned short* __restrict__ Ahi,
                                               const unsigned short* __restrict__ Alo,
                                               const unsigned short* __restrict__ Bhi,
                                               const unsigned short* __restrict__ Blo,
                                               const float* __restrict__ wsb,
                                               float* __restrict__ out) {
  __shared__ __align__(16) unsigned short Ah[64][40], Al[64][40];
  __shared__ __align__(16) unsigned short Bh[128][40], Bl[128][40];
  int tid = threadIdx.x, lane = tid & 63, w = tid >> 6;
  int lb = (int)(blockIdx.x & 7) * 128 + (int)(blockIdx.x >> 3);  // XCD swizzle (1024%8==0)
  int by = lb >> 3, bx = lb & 7;
  int row0 = by * 64, cn0 = bx * 128;
  int wr = w & 1, wc = w >> 1;
  int sar = tid >> 2, sak = (tid & 3) * 8;    // A staging: 64 rows x 4 16B-chunks
  int sbc = tid >> 1, sbk = (tid & 1) * 16;   // B staging: 128 cols x 2 32B-chunks
  int fr = lane & 15, kq = (lane >> 4) * 8;
  f32x4 acc[2][4] = {};

  for (int ks = 0; ks < 9; ++ks) {
    int k0 = ks * 32;
    *(uint4*)&Ah[sar][sak] = *(const uint4*)&Ahi[(size_t)(row0+sar)*KP + k0 + sak];
    *(uint4*)&Al[sar][sak] = *(const uint4*)&Alo[(size_t)(row0+sar)*KP + k0 + sak];
    *(uint4*)&Bh[sbc][sbk]     = *(const uint4*)&Bhi[(size_t)(cn0+sbc)*KP + k0 + sbk];
    *(uint4*)&Bh[sbc][sbk + 8] = *(const uint4*)&Bhi[(size_t)(cn0+sbc)*KP + k0 + sbk + 8];
    *(uint4*)&Bl[sbc][sbk]     = *(const uint4*)&Blo[(size_t)(cn0+sbc)*KP + k0 + sbk];
    *(uint4*)&Bl[sbc][sbk + 8] = *(const uint4*)&Blo[(size_t)(cn0+sbc)*KP + k0 + sbk + 8];
    __syncthreads();
    short8 ah[2], alr[2], bh[4], blr[4];
    #pragma unroll
    for (int rg = 0; rg < 2; ++rg) {
      ah[rg]  = *(const short8*)&Ah[wr*32 + rg*16 + fr][kq];
      alr[rg] = *(const short8*)&Al[wr*32 + rg*16 + fr][kq];
    }
    #pragma unroll
    for (int cg = 0; cg < 4; ++cg) {
      bh[cg]  = *(const short8*)&Bh[wc*64 + cg*16 + fr][kq];
      blr[cg] = *(const short8*)&Bl[wc*64 + cg*16 + fr][kq];
    }
    #pragma unroll
    for (int rg = 0; rg < 2; ++rg)
      #pragma unroll
      for (int cg = 0; cg < 4; ++cg) {
        acc[rg][cg] = __builtin_amdgcn_mfma_f32_16x16x32_bf16(ah[rg],  bh[cg],  acc[rg][cg], 0, 0, 0);
        acc[rg][cg] = __builtin_amdgcn_mfma_f32_16x16x32_bf16(ah[rg],  blr[cg], acc[rg][cg], 0, 0, 0);
        acc[rg][cg] = __builtin_amdgcn_mfma_f32_16x16x32_bf16(alr[rg], bh[cg],  acc[rg][cg], 0, 0, 0);
      }
    __syncthreads();
  }
  #pragma unroll
  for (int rg = 0; rg < 2; ++rg)
    #pragma unroll
    for (int cg = 0; cg < 4; ++cg) {
      int col = cn0 + wc*64 + cg*16 + fr;
      float bb = wsb[col];
      #pragma unroll
      for (int q = 0; q < 4; ++q) {
        int row = row0 + wr*32 + rg*16 + (lane >> 4)*4 + q;
        out[OUT_NS + (size_t)row*NSc + col] = acc[rg][cg][q] + bb;
      }
    }
}

// ---------------- Kernel C: edge features + GVP + LN, weights via uniform loads ----
// GVP weights read directly from global with wave-uniform compile-time-offset
// addresses (-> s_load/K$ or L1-broadcast on the idle VMEM pipe). This removes
// the 1120 broadcast ds_read_b32/thread that saturated the per-CU LDS pipe
// (~40us of the 62us). LDS keeps only the ES/EV output staging.
__global__ __launch_bounds__(256) void kedge(const float* __restrict__ coords,
    const int* __restrict__ resid,
    const float* __restrict__ ewh, const float* __restrict__ eww,
    const float* __restrict__ ewb, const float* __restrict__ ewv,
    const float* __restrict__ elg, const float* __restrict__ elb,
    const float* __restrict__ ws, float* __restrict__ out) {
  __shared__ float es[256*33];
  int tid = threadIdx.x;
  int e = blockIdx.x * 256 + tid;
  int b = e / (Lc*Kc);
  int rem = e - b*(Lc*Kc);
  int i = rem / Kc;
  int row = b*Lc + i;
  const int* eix = (const int*)(ws + WS_EIX);
  int j = eix[e];
  float Dn = ws[WS_EDS + e];
  bool jok = ((unsigned)j < (unsigned)Lc);
  bool valid = jok && (Dn < 5e7f) && (Dn < 5e9f);
  int sj = jok ? j : 0;

  int dcl = resid[row] - resid[b*Lc + sj];
  dcl = dcl < -32 ? -32 : (dcl > 32 ? 32 : dcl);
  float dpos = (float)dcl;
  float s[35];
  #pragma unroll
  for (int m = 0; m < 16; ++m) {
    float c = (20.f/15.f) * (float)m;
    float z = (Dn - c) * 0.8f;
    s[m] = expf(-z*z);
  }
  #pragma unroll
  for (int m = 0; m < 8; ++m) {
    float fr = expf((float)(2*m) * (-0.57564627324851148f));
    float ang = dpos * fr;
    s[16+m] = cosf(ang);
    s[24+m] = sinf(ang);
  }
  float csf = ws[WS_CMF + row];
  float cdf = ws[WS_CMF + b*Lc + sj];
  s[32] = 1.f - csf; s[33] = 1.f - cdf;
  const float* Xb = coords + (size_t)b*Lc*9;
  float vx = Xb[i*9+3] - Xb[sj*9+3];
  float vy = Xb[i*9+4] - Xb[sj*9+4];
  float vz = Xb[i*9+5] - Xb[sj*9+5];
  float ss2 = vx*vx + vy*vy + vz*vz;
  float inv = 1.f / sqrtf(ss2 + 1e-8f);
  float e0 = vx*inv, e1 = vy*inv, e2 = vz*inv;
  if (!isfinite(e0)) e0 = 0.f;
  if (!isfinite(e1)) e1 = 0.f;
  if (!isfinite(e2)) e2 = 0.f;
  float wh00 = ewh[0], wv00 = ewv[0];
  float vh0 = e0*wh00, vh1 = e1*wh00, vh2 = e2*wh00;
  s[34] = sqrtf(fmaxf(vh0*vh0 + vh1*vh1 + vh2*vh2, 1e-8f));

  // GVP matmul: weights from global (uniform address, scalar-cache resident)
  float o[32]; float sm = 0.f;
  #pragma unroll
  for (int c4 = 0; c4 < 8; ++c4) {
    float4 a4 = *(const float4*)&ewb[c4*4];
    #pragma unroll
    for (int q = 0; q < 35; ++q) {
      float4 w4 = *(const float4*)&eww[q*32 + c4*4];
      a4.x = fmaf(s[q], w4.x, a4.x);
      a4.y = fmaf(s[q], w4.y, a4.y);
      a4.z = fmaf(s[q], w4.z, a4.z);
      a4.w = fmaf(s[q], w4.w, a4.w);
    }
    o[c4*4+0]=a4.x; o[c4*4+1]=a4.y; o[c4*4+2]=a4.z; o[c4*4+3]=a4.w;
    sm += a4.x; sm += a4.y; sm += a4.z; sm += a4.w;
  }
  float mu = sm * (1.f/32.f);
  float sq = 0.f;
  #pragma unroll
  for (int c = 0; c < 32; ++c) { float dd = o[c]-mu; sq += dd*dd; }
  float isd = 1.f / sqrtf(sq*(1.f/32.f) + 1e-4f);
  float vo0 = vh0*wv00, vo1 = vh1*wv00, vo2 = vh2*wv00;
  float vn2 = fmaxf(vo0*vo0 + vo1*vo1 + vo2*vo2, 1e-8f);
  float ivn = 1.f / sqrtf(vn2);

  // ---- ES: stage -> coalesced float4 (gamma/beta also uniform global loads) ----
  #pragma unroll
  for (int c4 = 0; c4 < 8; ++c4) {
    float4 g4 = *(const float4*)&elg[c4*4];
    float4 b4 = *(const float4*)&elb[c4*4];
    es[tid*33 + c4*4 + 0] = valid ? ((o[c4*4+0]-mu)*isd*g4.x + b4.x) : 0.f;
    es[tid*33 + c4*4 + 1] = valid ? ((o[c4*4+1]-mu)*isd*g4.y + b4.y) : 0.f;
    es[tid*33 + c4*4 + 2] = valid ? ((o[c4*4+2]-mu)*isd*g4.z + b4.z) : 0.f;
    es[tid*33 + c4*4 + 3] = valid ? ((o[c4*4+3]-mu)*isd*g4.w + b4.w) : 0.f;
  }
  out[OUT_EI + e]       = valid ? (float)row : -1.f;
  out[OUT_EI + NEc + e] = valid ? (float)(b*Lc + j) : -1.f;
  __syncthreads();
  {
    size_t base32 = OUT_ES + (size_t)blockIdx.x * 256 * 32;
    #pragma unroll
    for (int k = 0; k < 8; ++k) {
      int flat = (k*256 + tid) * 4;
      int el = flat >> 5, c0 = flat & 31;
      float4 vq = {es[el*33+c0], es[el*33+c0+1], es[el*33+c0+2], es[el*33+c0+3]};
      *(float4*)&out[base32 + flat] = vq;
    }
  }
  __syncthreads();
  // ---- EV: stage -> coalesced float4 (reuse es) ----
  es[tid*3 + 0] = valid ? vo0*ivn : 0.f;
  es[tid*3 + 1] = valid ? vo1*ivn : 0.f;
  es[tid*3 + 2] = valid ? vo2*ivn : 0.f;
  __syncthreads();
  if (tid < 192) {
    size_t base3 = OUT_EV + (size_t)blockIdx.x * 768;
    float4 vq = {es[tid*4], es[tid*4+1], es[tid*4+2], es[tid*4+3]};
    *(float4*)&out[base3 + tid*4] = vq;
  }
}

// ---------------- Kernel D4: node LayerNorm + confidence RBF term ----------------
__global__ __launch_bounds__(256) void kln_node(const float* __restrict__ conf,
    const float* __restrict__ cw, const float* __restrict__ cb,
    const float* __restrict__ lg, const float* __restrict__ lb,
    float* __restrict__ out) {
  int n = blockIdx.x, tid = threadIdx.x;
  size_t base = OUT_NS + (size_t)n*NSc;
  float x0 = out[base + tid];
  float x1 = out[base + tid + 256];
  float x2 = out[base + tid + 512];
  float x3 = out[base + tid + 768];
  float sm = x0+x1+x2+x3;
  float sq = x0*x0+x1*x1+x2*x2+x3*x3;
  int lane = tid & 63, wid = tid >> 6;
  #pragma unroll
  for (int off = 32; off > 0; off >>= 1) { sm += __shfl_down(sm, off); sq += __shfl_down(sq, off); }
  __shared__ float rs[4], rq[4];
  if (lane == 0) { rs[wid] = sm; rq[wid] = sq; }
  __syncthreads();
  sm = rs[0]+rs[1]+rs[2]+rs[3];
  sq = rq[0]+rq[1]+rq[2]+rq[3];
  float mu = sm * (1.f/1024.f);
  float var = fmaxf(sq * (1.f/1024.f) - mu*mu, 0.f);
  float isd = 1.f / sqrtf(var + 1e-4f);
  float cf = conf[n];
  float rb[16];
  #pragma unroll
  for (int m = 0; m < 16; ++m) {
    float z = (cf - (float)m*(1.f/15.f)) * 16.f;
    rb[m] = expf(-z*z);
  }
  float xs_[4] = {x0, x1, x2, x3};
  #pragma unroll
  for (int q = 0; q < 4; ++q) {
    int c = tid + q*256;
    float t = cb[c];
    #pragma unroll
    for (int m = 0; m < 16; ++m) t = fmaf(rb[m], cw[m*1024 + c], t);
    out[base + c] = (xs_[q]-mu)*isd*lg[c] + lb[c] + t;
  }
}

extern "C" void kernel_launch(void* const* d_in, const int* in_sizes, int n_in,
                              void* d_out, int out_size, void* d_ws, size_t ws_size,
                              hipStream_t stream) {
  const float* coords         = (const float*)d_in[0];
  const unsigned char* cmask  = (const unsigned char*)d_in[1];
  const int* resid            = (const int*)d_in[2];
  const unsigned char* pmask  = (const unsigned char*)d_in[3];
  const float* conf           = (const float*)d_in[4];
  const float* nwh            = (const float*)d_in[5];
  const float* nww            = (const float*)d_in[6];
  const float* nwb            = (const float*)d_in[7];
  const float* nwv            = (const float*)d_in[8];
  const float* nlg            = (const float*)d_in[9];
  const float* nlb            = (const float*)d_in[10];
  const float* ewh            = (const float*)d_in[11];
  const float* eww            = (const float*)d_in[12];
  const float* ewb            = (const float*)d_in[13];
  const float* ewv            = (const float*)d_in[14];
  const float* elg            = (const float*)d_in[15];
  const float* elb            = (const float*)d_in[16];
  const float* cw             = (const float*)d_in[17];
  const float* cb             = (const float*)d_in[18];
  float* out = (float*)d_out;
  float* ws  = (float*)d_ws;
  float* esbase = out + OUT_ES;                  // ES region scratch (consumed pre-kedge)
  float4* whwv4 = (float4*)esbase;               // 256 float4
  float4* wht4  = whwv4 + 256;                   // 256 float4
  unsigned short* Ahi = (unsigned short*)(esbase + 2048);
  unsigned short* Alo = Ahi + (size_t)Nn * KP;
  unsigned short* BhiT = Alo + (size_t)Nn * KP;
  unsigned short* BloT = BhiT + (size_t)NSc * KP;
  float4* pack  = (float4*)(out + OUT_EV);       // packed Ca+flags (ev region)

  kinit<<<36, 256, 0, stream>>>(cmask, coords, resid, pmask, nwh, nwv, ws, pack, whwv4, wht4);
  knode_geom<<<Nn/64, 64, 0, stream>>>(coords, ws);
  kvnode<<<Nn/4, 256, 0, stream>>>(wht4, whwv4, ws, out);
  ktopk<<<Nn/4, 256, 0, stream>>>(pack, ws);
  kprepA<<<Nn, 64, 0, stream>>>(ws, Ahi, Alo);
  kprepB<<<288, 256, 0, stream>>>(nww, BhiT, BloT);
  kgemm_s<<<(Nn/64)*(NSc/128), 256, 0, stream>>>(Ahi, Alo, BhiT, BloT, nwb, out);
  kedge<<<NEc/256, 256, 0, stream>>>(coords, resid, ewh, eww, ewb, ewv, elg, elb, ws, out);
  kln_node<<<Nn, 256, 0, stream>>>(conf, cw, cb, nlg, nlb, out);
}

// Round 12
// 249.413 us; speedup vs baseline: 1.0957x; 1.0957x over previous
//
#include <hip/hip_runtime.h>
#include <math.h>

// ---- problem constants ----
constexpr int Bc = 4, Lc = 2048, Kc = 30;
constexpr int Nn = Bc * Lc;            // 8192 nodes
constexpr int NSc = 1024, NVc = 256;
constexpr int NEc = Nn * Kc;           // 245760 edges
constexpr int SK = 263;                // 7 + 256 scalar GVP input dim
constexpr int KP = 288;                // K padded to 9x32 for MFMA

// ---- d_out float offsets (outputs concatenated flat in return order) ----
constexpr size_t OUT_NS = 0;                                  // (8192,1024)
constexpr size_t OUT_NV = (size_t)Nn * NSc;                   // (8192,256,3)
constexpr size_t OUT_ES = OUT_NV + (size_t)Nn * NVc * 3;      // (245760,32)
constexpr size_t OUT_EV = OUT_ES + (size_t)NEc * 32;          // (245760,1,3)
constexpr size_t OUT_EI = OUT_EV + (size_t)NEc * 3;           // (2,245760) as float

// ---- workspace float offsets ----
constexpr size_t WS_SIN = 0;                                  // (8192,263) s_in
constexpr size_t WS_NDV = WS_SIN + (size_t)Nn * SK;           // (8192,9) node_v
constexpr size_t WS_EIX = WS_NDV + (size_t)Nn * 9;            // (245760) int E_idx
constexpr size_t WS_EDS = WS_EIX + (size_t)NEc;               // (245760) E_dist
constexpr size_t WS_CMF = WS_EDS + (size_t)NEc;               // (8192) canonical coord_mask float

using short8 = __attribute__((ext_vector_type(8))) short;   // 8 bf16 (4 VGPRs)
using f32x4  = __attribute__((ext_vector_type(4))) float;   // 4 fp32 acc

__device__ __forceinline__ void norml3(float& x, float& y, float& z) {
  float ss = x*x + y*y + z*z;
  float inv = 1.0f / sqrtf(ss + 1e-8f);
  x *= inv; y *= inv; z *= inv;
}

// RNE split x = hi + lo (both exactly representable in bf16)
__device__ __forceinline__ void bf16split(float x, unsigned short& h, unsigned short& l) {
  unsigned u = __float_as_uint(x);
  unsigned hb = (u + 0x7FFFu + ((u >> 16) & 1u)) & 0xFFFF0000u;
  float lf = x - __uint_as_float(hb);
  unsigned ul = __float_as_uint(lf);
  h = (unsigned short)(hb >> 16);
  l = (unsigned short)((ul + 0x7FFFu + ((ul >> 16) & 1u)) >> 16);
}

// ---------------- Kernel I: merged kmask (blocks 0..31) + kwhwv (blocks 32..35) ----
__global__ __launch_bounds__(256) void kinit(const unsigned char* __restrict__ cm,
                                             const float* __restrict__ coords,
                                             const int* __restrict__ resid,
                                             const unsigned char* __restrict__ pmask,
                                             const float* __restrict__ wh,
                                             const float* __restrict__ wv,
                                             float* __restrict__ ws,
                                             float4* __restrict__ pack,
                                             float4* __restrict__ whwv4,
                                             float4* __restrict__ wht4) {
  __shared__ float r0[256], r1[256], r2[256];
  __shared__ int flag;
  int tid = threadIdx.x;
  if (blockIdx.x < 32) {
    if (tid == 0) flag = 0;
    __syncthreads();
    int any = 0;
    for (int p = tid; p < 1024; p += 256)
      if (p & 3) any |= cm[p];
    if (any) atomicOr(&flag, 1);
    __syncthreads();
    bool bytefmt = (flag != 0);
    int n = blockIdx.x * 256 + tid;
    unsigned char v = bytefmt ? cm[n] : cm[4*n];  // LE low byte of int32 0/1
    ws[WS_CMF + n] = v ? 1.f : 0.f;
    int rm = (pmask[n] == 0) ? 1 : 0;
    int w = (resid[n] << 2) | ((v ? 1 : 0) << 1) | rm;
    float4 p;
    p.x = coords[(size_t)n*9 + 3];
    p.y = coords[(size_t)n*9 + 4];
    p.z = coords[(size_t)n*9 + 5];
    p.w = __int_as_float(w);
    pack[n] = p;
  } else {
    int lane = tid & 63, wid = tid >> 6;
    int vcol = (int)(blockIdx.x - 32) * 64 + lane;
    float a0 = 0.f, a1 = 0.f, a2 = 0.f;
    #pragma unroll 4
    for (int hh = 0; hh < 64; ++hh) {
      int h = wid * 64 + hh;
      float wvv = wv[(size_t)h * 256 + vcol];
      a0 = fmaf(wh[h],       wvv, a0);
      a1 = fmaf(wh[256 + h], wvv, a1);
      a2 = fmaf(wh[512 + h], wvv, a2);
    }
    r0[tid] = a0; r1[tid] = a1; r2[tid] = a2;
    __syncthreads();
    if (wid == 0) {
      a0 = r0[lane] + r0[lane+64] + r0[lane+128] + r0[lane+192];
      a1 = r1[lane] + r1[lane+64] + r1[lane+128] + r1[lane+192];
      a2 = r2[lane] + r2[lane+64] + r2[lane+128] + r2[lane+192];
      whwv4[vcol] = float4{a0, a1, a2, 0.f};
    } else if (wid == 1) {
      wht4[vcol] = float4{wh[vcol], wh[256 + vcol], wh[512 + vcol], 0.f};
    }
  }
}

// ---------------- Kernel A: per-node geometric features (64-thread blocks) --------
__global__ __launch_bounds__(64) void knode_geom(const float* __restrict__ coords,
                                                 float* __restrict__ ws) {
  int n = blockIdx.x * 64 + threadIdx.x;
  if (n >= Nn) return;
  int b = n / Lc, l = n % Lc;
  const float* Xb = coords + (size_t)b * Lc * 9;
  float ax[7][3];
  #pragma unroll
  for (int m = 0; m < 7; ++m) {
    int t = 3*l + m - 2;
    if (t >= 0 && t < 3*Lc) { ax[m][0]=Xb[t*3+0]; ax[m][1]=Xb[t*3+1]; ax[m][2]=Xb[t*3+2]; }
    else { ax[m][0]=0.f; ax[m][1]=0.f; ax[m][2]=0.f; }
  }
  float U[5][3];
  #pragma unroll
  for (int mi = 0; mi < 5; ++mi) {
    int t = 3*l - 1 + mi;
    if (t >= 0 && t <= 3*Lc - 2) {
      float x = ax[mi+2][0]-ax[mi+1][0], y = ax[mi+2][1]-ax[mi+1][1], z = ax[mi+2][2]-ax[mi+1][2];
      norml3(x,y,z);
      U[mi][0]=x; U[mi][1]=y; U[mi][2]=z;
    } else { U[mi][0]=0.f; U[mi][1]=0.f; U[mi][2]=0.f; }
  }
  float cph[3], sph[3];
  #pragma unroll
  for (int a = 0; a < 3; ++a) {
    int t = 3*l + a - 1;
    if (t < 0 || t > 3*Lc - 4) { cph[a] = 1.f; sph[a] = 0.f; continue; }
    const float *u2 = U[a], *u1 = U[a+1], *u0 = U[a+2];
    float n2x = u2[1]*u1[2]-u2[2]*u1[1], n2y = u2[2]*u1[0]-u2[0]*u1[2], n2z = u2[0]*u1[1]-u2[1]*u1[0];
    norml3(n2x,n2y,n2z);
    float n1x = u1[1]*u0[2]-u1[2]*u0[1], n1y = u1[2]*u0[0]-u1[0]*u0[2], n1z = u1[0]*u0[1]-u1[1]*u0[0];
    norml3(n1x,n1y,n1z);
    float cd = n2x*n1x + n2y*n1y + n2z*n1z;
    cd = fminf(fmaxf(cd, -1.f + 1e-7f), 1.f - 1e-7f);
    float dt = u2[0]*n1x + u2[1]*n1y + u2[2]*n1z;
    float sg = (dt > 0.f) ? 1.f : ((dt < 0.f) ? -1.f : 0.f);
    float D = sg * acosf(cd);
    cph[a] = cosf(D); sph[a] = sinf(D);
  }
  float fx=0.f,fy=0.f,fz=0.f, kx=0.f,ky=0.f,kz=0.f;
  if (l < Lc-1) { fx=ax[6][0]-ax[3][0]; fy=ax[6][1]-ax[3][1]; fz=ax[6][2]-ax[3][2]; norml3(fx,fy,fz); }
  if (l > 0)    { kx=ax[0][0]-ax[3][0]; ky=ax[0][1]-ax[3][1]; kz=ax[0][2]-ax[3][2]; norml3(kx,ky,kz); }
  float cx=ax[4][0]-ax[3][0], cy=ax[4][1]-ax[3][1], cz=ax[4][2]-ax[3][2]; norml3(cx,cy,cz);
  float nx=ax[2][0]-ax[3][0], ny=ax[2][1]-ax[3][1], nz=ax[2][2]-ax[3][2]; norml3(nx,ny,nz);
  float bix=cx+nx, biy=cy+ny, biz=cz+nz; norml3(bix,biy,biz);
  float px=cy*nz-cz*ny, py=cz*nx-cx*nz, pz=cx*ny-cy*nx; norml3(px,py,pz);
  const float c1 = 0.57735026f, c2 = 0.81649658f;
  float sx = -bix*c1 - px*c2, sy = -biy*c1 - py*c2, sz = -biz*c1 - pz*c2;

  float cmf = ws[WS_CMF + n];
  float* sr = ws + WS_SIN + (size_t)n * SK;
  sr[0]=cph[0]; sr[1]=cph[1]; sr[2]=cph[2]; sr[3]=sph[0]; sr[4]=sph[1]; sr[5]=sph[2]; sr[6]=cmf;
  float* vr = ws + WS_NDV + (size_t)n * 9;
  vr[0]=fx; vr[1]=fy; vr[2]=fz; vr[3]=kx; vr[4]=ky; vr[5]=kz; vr[6]=sx; vr[7]=sy; vr[8]=sz;
}

// ---------------- Kernel V: fused node vector path (dense float4 NV stores) -------
__global__ __launch_bounds__(256) void kvnode(const float4* __restrict__ wht4,
                                              const float4* __restrict__ whwv4,
                                              float* __restrict__ ws,
                                              float* __restrict__ out) {
  int tid = threadIdx.x, lane = tid & 63, wid = tid >> 6;
  int n = blockIdx.x * 4 + wid;
  const float* v = ws + WS_NDV + (size_t)n * 9;
  float v00=v[0],v01=v[1],v02=v[2];
  float v10=v[3],v11=v[4],v12=v[5];
  float v20=v[6],v21=v[7],v22=v[8];
  float p = 0.f;
  float vo[4][3];
  #pragma unroll
  for (int m = 0; m < 4; ++m) {
    int hv = lane + 64*m;
    float4 wt = wht4[hv];
    float vh0 = v00*wt.x + v10*wt.y + v20*wt.z;
    float vh1 = v01*wt.x + v11*wt.y + v21*wt.z;
    float vh2 = v02*wt.x + v12*wt.y + v22*wt.z;
    ws[WS_SIN + (size_t)n*SK + 7 + hv] = sqrtf(fmaxf(vh0*vh0 + vh1*vh1 + vh2*vh2, 1e-8f));
    int ho = lane*4 + m;
    float4 wc = whwv4[ho];
    float o0 = v00*wc.x + v10*wc.y + v20*wc.z;
    float o1 = v01*wc.x + v11*wc.y + v21*wc.z;
    float o2 = v02*wc.x + v12*wc.y + v22*wc.z;
    vo[m][0]=o0; vo[m][1]=o1; vo[m][2]=o2;
    p += fmaxf(o0*o0 + o1*o1 + o2*o2, 1e-8f);
  }
  #pragma unroll
  for (int off = 1; off < 64; off <<= 1) p += __shfl_xor(p, off);
  float isd = 1.f / sqrtf(p * (1.f/256.f));
  size_t o = OUT_NV + (size_t)n*768 + (size_t)lane*12;
  float4 f0 = {vo[0][0]*isd, vo[0][1]*isd, vo[0][2]*isd, vo[1][0]*isd};
  float4 f1 = {vo[1][1]*isd, vo[1][2]*isd, vo[2][0]*isd, vo[2][1]*isd};
  float4 f2 = {vo[2][2]*isd, vo[3][0]*isd, vo[3][1]*isd, vo[3][2]*isd};
  *(float4*)&out[o+0] = f0;
  *(float4*)&out[o+4] = f1;
  *(float4*)&out[o+8] = f2;
}

// ---------------- Kernel B: wave-autonomous exact top-30 threshold select --------
__global__ __launch_bounds__(256) void ktopk(const float4* __restrict__ pack,
                                             float* __restrict__ ws) {
  __shared__ unsigned long long cbuf[4][256];
  int tid = threadIdx.x, lane = tid & 63, wid = tid >> 6;
  int row = blockIdx.x * 4 + wid;
  int b = row >> 11;
  int i = row & (Lc - 1);
  const float4* P = pack + (size_t)b * Lc;
  int* eix = (int*)(ws + WS_EIX);
  unsigned long long lmask_lt = (1ULL << lane) - 1ULL;

  float4 pi = P[i];
  int wi = __float_as_int(pi.w);
  float cmi = ((wi >> 1) & 1) ? 1.f : 0.f;
  float rmi = (wi & 1) ? 1.f : 0.f;
  int ri = wi >> 2;

  unsigned a[32];
  unsigned lmin = 0xFFFFFFFFu;
  #pragma unroll
  for (int half = 0; half < 2; ++half) {
    float4 pjs[16];
    #pragma unroll
    for (int q = 0; q < 16; ++q)
      pjs[q] = P[lane + 64*(half*16 + q)];
    #pragma unroll
    for (int q = 0; q < 16; ++q) {
      int m = half*16 + q;
      int j = lane + 64*m;
      float4 pj = pjs[q];
      int wj = __float_as_int(pj.w);
      float cmj = ((wj >> 1) & 1) ? 1.f : 0.f;
      float rmj = (wj & 1) ? 1.f : 0.f;
      float dx = __fsub_rn(pi.x, pj.x);
      float dy = __fsub_rn(pi.y, pj.y);
      float dz = __fsub_rn(pi.z, pj.z);
      float ss = __fadd_rn(__fadd_rn(__fmul_rn(dx,dx), __fmul_rn(dy,dy)), __fmul_rn(dz,dz));
      float dist = __fsqrt_rn(__fadd_rn(ss, 1e-8f));
      float cm2 = __fmul_rn(cmi, cmj);
      float D = __fmul_rn(cm2, dist);
      int ad = ri - (wj >> 2); ad = ad < 0 ? -ad : ad;
      float covm = (ad <= 3) ? 0.f : 1.f;
      float dseq = (float)(i >= j ? i - j : j - i);
      float t1 = __fmul_rn(__fsub_rn(1.f, cm2), __fadd_rn(1e8f, __fmul_rn(dseq, 1e6f)));
      float rm2 = __fmul_rn(rmi, rmj);
      float t2 = __fmul_rn(__fsub_rn(1.f, rm2), 1e10f);
      float adj = __fadd_rn(__fadd_rn(__fmul_rn(D, covm), t1), t2);
      unsigned u = __float_as_uint(adj);   // adj >= 0 -> order-preserving bits
      a[m] = u;
      lmin = u < lmin ? u : lmin;
    }
  }

  // Tv = 30th-smallest lane-min. hi covers all possible adj (< 1.3e10 < 3.4e10).
  unsigned lo = 0u, hi = 0x51000000u;
  while (lo < hi) {
    unsigned mid = lo + ((hi - lo) >> 1);
    unsigned long long bal = __ballot(lmin <= mid);
    if (__popcll(bal) >= Kc) hi = mid; else lo = mid + 1u;
  }
  unsigned Tv = lo;

  // compact survivors into cbuf in (m, lane) order
  unsigned base = 0;
  #pragma unroll
  for (int m = 0; m < 32; ++m) {
    bool pred = (a[m] <= Tv);
    unsigned long long bal = __ballot(pred);
    if (pred) {
      unsigned pos = base + (unsigned)__popcll(bal & lmask_lt);
      if (pos < 256u)
        cbuf[wid][pos] = ((unsigned long long)a[m] << 32) | (unsigned)(lane + 64*m);
    }
    base += (unsigned)__popcll(bal);
  }
  unsigned M = base < 256u ? base : 256u;
  __builtin_amdgcn_wave_barrier();

  for (unsigned idx = (unsigned)lane; idx < M; idx += 64u) {
    unsigned long long k0 = cbuf[wid][idx];
    int rank = 0;
    for (unsigned t = 0; t < M; ++t) rank += (cbuf[wid][t] < k0) ? 1 : 0;
    if (rank < Kc) {
      int j = (int)(k0 & 2047ULL);
      float4 pj = P[j];
      int wj = __float_as_int(pj.w);
      float cmj = ((wj >> 1) & 1) ? 1.f : 0.f;
      float dx = __fsub_rn(pi.x, pj.x);
      float dy = __fsub_rn(pi.y, pj.y);
      float dz = __fsub_rn(pi.z, pj.z);
      float ss2 = __fadd_rn(__fadd_rn(__fmul_rn(dx,dx), __fmul_rn(dy,dy)), __fmul_rn(dz,dz));
      float dist = __fsqrt_rn(__fadd_rn(ss2, 1e-8f));
      float D = __fmul_rn(__fmul_rn(cmi, cmj), dist);
      eix[(size_t)row*Kc + rank] = j;
      ws[WS_EDS + (size_t)row*Kc + rank] = D;
    }
  }
}

// ---------------- Kernel P1: split s_in rows into bf16 hi/lo, K padded to 288 ------
__global__ __launch_bounds__(64) void kprepA(const float* __restrict__ ws,
                                             unsigned short* __restrict__ Ahi,
                                             unsigned short* __restrict__ Alo) {
  int n = blockIdx.x, t = threadIdx.x;
  const float* src = ws + WS_SIN + (size_t)n * SK;
  size_t dst = (size_t)n * KP;
  #pragma unroll
  for (int p = 0; p < 5; ++p) {
    int k = t + 64*p;
    if (k >= KP) break;
    float x = (k < SK) ? src[k] : 0.f;
    unsigned short h, l;
    bf16split(x, h, l);
    Ahi[dst + k] = h;
    Alo[dst + k] = l;
  }
}

// ---------------- Kernel P2: transpose weight -> bf16 hi/lo B^T[1024][288] ---------
__global__ __launch_bounds__(256) void kprepB(const float* __restrict__ wsw,
                                              unsigned short* __restrict__ Bhi,
                                              unsigned short* __restrict__ Blo) {
  __shared__ float tile[32][33];
  int bidx = blockIdx.x;           // 9 k-tiles x 32 c-tiles
  int kt = bidx % 9, ct = bidx / 9;
  int k0 = kt*32, c0 = ct*32;
  int t = threadIdx.x;
  int r = t >> 5, c = t & 31;
  #pragma unroll
  for (int p = 0; p < 4; ++p) {
    int k = k0 + r + 8*p;
    tile[r + 8*p][c] = (k < SK) ? wsw[(size_t)k*NSc + c0 + c] : 0.f;
  }
  __syncthreads();
  int cc = t >> 3, kq = (t & 7) * 4;
  ushort4 h4, l4;
  float x0 = tile[kq+0][cc], x1 = tile[kq+1][cc], x2 = tile[kq+2][cc], x3 = tile[kq+3][cc];
  bf16split(x0, h4.x, l4.x);
  bf16split(x1, h4.y, l4.y);
  bf16split(x2, h4.z, l4.z);
  bf16split(x3, h4.w, l4.w);
  size_t o = (size_t)(c0 + cc) * KP + k0 + kq;
  *(ushort4*)&Bhi[o] = h4;
  *(ushort4*)&Blo[o] = l4;
}

// ---------------- Kernel D2: S GEMM via MFMA, split-bf16 (3-term Markidis) --------
__global__ __launch_bounds__(256) void kgemm_s(const unsigned short* __restrict__ Ahi,
                                               const unsigned short* __restrict__ Alo,
                                               const unsigned short* __restrict__ Bhi,
                                               const unsigned short* __restrict__ Blo,
                                               const float* __restrict__ wsb,
                                               float* __restrict__ out) {
  __shared__ __align__(16) unsigned short Ah[64][40], Al[64][40];
  __shared__ __align__(16) unsigned short Bh[128][40], Bl[128][40];
  int tid = threadIdx.x, lane = tid & 63, w = tid >> 6;
  int lb = (int)(blockIdx.x & 7) * 128 + (int)(blockIdx.x >> 3);  // XCD swizzle (1024%8==0)
  int by = lb >> 3, bx = lb & 7;
  int row0 = by * 64, cn0 = bx * 128;
  int wr = w & 1, wc = w >> 1;
  int sar = tid >> 2, sak = (tid & 3) * 8;    // A staging: 64 rows x 4 16B-chunks
  int sbc = tid >> 1, sbk = (tid & 1) * 16;   // B staging: 128 cols x 2 32B-chunks
  int fr = lane & 15, kq = (lane >> 4) * 8;
  f32x4 acc[2][4] = {};

  for (int ks = 0; ks < 9; ++ks) {
    int k0 = ks * 32;
    *(uint4*)&Ah[sar][sak] = *(const uint4*)&Ahi[(size_t)(row0+sar)*KP + k0 + sak];
    *(uint4*)&Al[sar][sak] = *(const uint4*)&Alo[(size_t)(row0+sar)*KP + k0 + sak];
    *(uint4*)&Bh[sbc][sbk]     = *(const uint4*)&Bhi[(size_t)(cn0+sbc)*KP + k0 + sbk];
    *(uint4*)&Bh[sbc][sbk + 8] = *(const uint4*)&Bhi[(size_t)(cn0+sbc)*KP + k0 + sbk + 8];
    *(uint4*)&Bl[sbc][sbk]     = *(const uint4*)&Blo[(size_t)(cn0+sbc)*KP + k0 + sbk];
    *(uint4*)&Bl[sbc][sbk + 8] = *(const uint4*)&Blo[(size_t)(cn0+sbc)*KP + k0 + sbk + 8];
    __syncthreads();
    short8 ah[2], alr[2], bh[4], blr[4];
    #pragma unroll
    for (int rg = 0; rg < 2; ++rg) {
      ah[rg]  = *(const short8*)&Ah[wr*32 + rg*16 + fr][kq];
      alr[rg] = *(const short8*)&Al[wr*32 + rg*16 + fr][kq];
    }
    #pragma unroll
    for (int cg = 0; cg < 4; ++cg) {
      bh[cg]  = *(const short8*)&Bh[wc*64 + cg*16 + fr][kq];
      blr[cg] = *(const short8*)&Bl[wc*64 + cg*16 + fr][kq];
    }
    #pragma unroll
    for (int rg = 0; rg < 2; ++rg)
      #pragma unroll
      for (int cg = 0; cg < 4; ++cg) {
        acc[rg][cg] = __builtin_amdgcn_mfma_f32_16x16x32_bf16(ah[rg],  bh[cg],  acc[rg][cg], 0, 0, 0);
        acc[rg][cg] = __builtin_amdgcn_mfma_f32_16x16x32_bf16(ah[rg],  blr[cg], acc[rg][cg], 0, 0, 0);
        acc[rg][cg] = __builtin_amdgcn_mfma_f32_16x16x32_bf16(alr[rg], bh[cg],  acc[rg][cg], 0, 0, 0);
      }
    __syncthreads();
  }
  #pragma unroll
  for (int rg = 0; rg < 2; ++rg)
    #pragma unroll
    for (int cg = 0; cg < 4; ++cg) {
      int col = cn0 + wc*64 + cg*16 + fr;
      float bb = wsb[col];
      #pragma unroll
      for (int q = 0; q < 4; ++q) {
        int row = row0 + wr*32 + rg*16 + (lane >> 4)*4 + q;
        out[OUT_NS + (size_t)row*NSc + col] = acc[rg][cg][q] + bb;
      }
    }
}

// ---------------- Kernel C: edge features + GVP via MFMA + LN ----------------------
// Per block: 256 edges. The GVP matmul S[256][35] @ W[35][32] is computed as
// split-bf16 MFMA over K=32 (s[0..31]) + full-f32 VALU tail (s32,s33,s34 terms).
// LDS layout (49KB, union): region0 40KB = A hi/lo [256][40]-bf16, later reused
// as es[256][36] f32 staging; region1 = B^T hi/lo [32][40]; region2 = st[256][4].
__global__ __launch_bounds__(256) void kedge(const float* __restrict__ coords,
    const int* __restrict__ resid,
    const float* __restrict__ ewh, const float* __restrict__ eww,
    const float* __restrict__ ewb, const float* __restrict__ ewv,
    const float* __restrict__ elg, const float* __restrict__ elb,
    const float* __restrict__ ws, float* __restrict__ out) {
  __shared__ __align__(16) unsigned char smem[50176];
  unsigned short* Ahh = (unsigned short*)smem;             // [256][40] bf16 hi
  unsigned short* All = (unsigned short*)(smem + 20480);   // [256][40] bf16 lo
  float* es = (float*)smem;                                // [256][36] (reuse after MFMA)
  unsigned short* Bhh = (unsigned short*)(smem + 40960);   // [32][40]
  unsigned short* Bll = (unsigned short*)(smem + 43520);   // [32][40]
  float* st = (float*)(smem + 46080);                      // [256][4] tail + valid

  int tid = threadIdx.x, lane = tid & 63, wv = tid >> 6;
  int e = blockIdx.x * 256 + tid;
  int b = e / (Lc*Kc);
  int rem = e - b*(Lc*Kc);
  int i = rem / Kc;
  int row = b*Lc + i;
  const int* eix = (const int*)(ws + WS_EIX);
  int j = eix[e];
  float Dn = ws[WS_EDS + e];
  bool jok = ((unsigned)j < (unsigned)Lc);
  bool valid = jok && (Dn < 5e7f) && (Dn < 5e9f);
  int sj = jok ? j : 0;

  int dcl = resid[row] - resid[b*Lc + sj];
  dcl = dcl < -32 ? -32 : (dcl > 32 ? 32 : dcl);
  float dpos = (float)dcl;
  float s[35];
  #pragma unroll
  for (int m = 0; m < 16; ++m) {
    float c = (20.f/15.f) * (float)m;
    float z = (Dn - c) * 0.8f;
    s[m] = expf(-z*z);
  }
  #pragma unroll
  for (int m = 0; m < 8; ++m) {
    float fr_ = expf((float)(2*m) * (-0.57564627324851148f));
    float ang = dpos * fr_;
    s[16+m] = cosf(ang);
    s[24+m] = sinf(ang);
  }
  float csf = ws[WS_CMF + row];
  float cdf = ws[WS_CMF + b*Lc + sj];
  s[32] = 1.f - csf; s[33] = 1.f - cdf;
  const float* Xb = coords + (size_t)b*Lc*9;
  float vx = Xb[i*9+3] - Xb[sj*9+3];
  float vy = Xb[i*9+4] - Xb[sj*9+4];
  float vz = Xb[i*9+5] - Xb[sj*9+5];
  float ss2 = vx*vx + vy*vy + vz*vz;
  float inv = 1.f / sqrtf(ss2 + 1e-8f);
  float e0 = vx*inv, e1 = vy*inv, e2 = vz*inv;
  if (!isfinite(e0)) e0 = 0.f;
  if (!isfinite(e1)) e1 = 0.f;
  if (!isfinite(e2)) e2 = 0.f;
  float wh00 = ewh[0], wv00 = ewv[0];
  float vh0 = e0*wh00, vh1 = e1*wh00, vh2 = e2*wh00;
  s[34] = sqrtf(fmaxf(vh0*vh0 + vh1*vh1 + vh2*vh2, 1e-8f));
  float vo0 = vh0*wv00, vo1 = vh1*wv00, vo2 = vh2*wv00;
  float vn2 = fmaxf(vo0*vo0 + vo1*vo1 + vo2*vo2, 1e-8f);
  float ivn = 1.f / sqrtf(vn2);
  float ev0 = vo0*ivn, ev1 = vo1*ivn, ev2 = vo2*ivn;

  // EI (coalesced, global)
  out[OUT_EI + e]       = valid ? (float)row : -1.f;
  out[OUT_EI + NEc + e] = valid ? (float)(b*Lc + j) : -1.f;

  // stage A rows (bf16 hi/lo, chunked 8-at-a-time), tail, and B^T tiles
  #pragma unroll
  for (int c = 0; c < 4; ++c) {
    short8 h8, l8;
    #pragma unroll
    for (int k = 0; k < 8; ++k) {
      unsigned short hh, ll;
      bf16split(s[c*8 + k], hh, ll);
      h8[k] = (short)hh; l8[k] = (short)ll;
    }
    *(short8*)&Ahh[tid*40 + c*8] = h8;
    *(short8*)&All[tid*40 + c*8] = l8;
  }
  *(float4*)&st[tid*4] = float4{s[32], s[33], s[34], valid ? 1.f : 0.f};
  {
    int bc = tid & 31, qg = tid >> 5;   // 8 groups x 4 q each -> q in [0,32)
    #pragma unroll
    for (int qi = 0; qi < 4; ++qi) {
      int q = qg*4 + qi;
      unsigned short hh, ll;
      bf16split(eww[q*32 + bc], hh, ll);
      Bhh[bc*40 + q] = hh;
      Bll[bc*40 + q] = ll;
    }
  }
  __syncthreads();

  // MFMA: wave wv covers edges ew..ew+63 (4 m-tiles); N=32 (2 n-tiles); K=32.
  int fr = lane & 15, kq = (lane >> 4) * 8;
  int ew = wv * 64;
  short8 bh[2], bl[2];
  #pragma unroll
  for (int nt = 0; nt < 2; ++nt) {
    bh[nt] = *(const short8*)&Bhh[(nt*16 + fr)*40 + kq];
    bl[nt] = *(const short8*)&Bll[(nt*16 + fr)*40 + kq];
  }
  f32x4 acc[4][2] = {};
  #pragma unroll
  for (int mt = 0; mt < 4; ++mt) {
    short8 ah = *(const short8*)&Ahh[(ew + mt*16 + fr)*40 + kq];
    short8 al = *(const short8*)&All[(ew + mt*16 + fr)*40 + kq];
    #pragma unroll
    for (int nt = 0; nt < 2; ++nt) {
      acc[mt][nt] = __builtin_amdgcn_mfma_f32_16x16x32_bf16(ah, bh[nt], acc[mt][nt], 0, 0, 0);
      acc[mt][nt] = __builtin_amdgcn_mfma_f32_16x16x32_bf16(ah, bl[nt], acc[mt][nt], 0, 0, 0);
      acc[mt][nt] = __builtin_amdgcn_mfma_f32_16x16x32_bf16(al, bh[nt], acc[mt][nt], 0, 0, 0);
    }
  }
  // VALU tail: + s32*W[32][c] + s33*W[33][c] + s34*W[34][c] (full f32)
  float w32[2], w33[2], w34[2];
  #pragma unroll
  for (int nt = 0; nt < 2; ++nt) {
    int cn = nt*16 + fr;
    w32[nt] = eww[32*32 + cn];
    w33[nt] = eww[33*32 + cn];
    w34[nt] = eww[34*32 + cn];
  }
  #pragma unroll
  for (int mt = 0; mt < 4; ++mt)
    #pragma unroll
    for (int q = 0; q < 4; ++q) {
      int r = ew + mt*16 + (lane >> 4)*4 + q;
      float4 sv = *(const float4*)&st[r*4];
      #pragma unroll
      for (int nt = 0; nt < 2; ++nt)
        acc[mt][nt][q] += sv.x*w32[nt] + sv.y*w33[nt] + sv.z*w34[nt];
    }
  __syncthreads();   // all A-fragment reads complete before es overwrites region0

  // write raw o to es[256][36]
  #pragma unroll
  for (int mt = 0; mt < 4; ++mt)
    #pragma unroll
    for (int q = 0; q < 4; ++q) {
      int r = ew + mt*16 + (lane >> 4)*4 + q;
      #pragma unroll
      for (int nt = 0; nt < 2; ++nt)
        es[r*36 + nt*16 + fr] = acc[mt][nt][q];
    }
  __syncthreads();

  // LN per edge (thread = own edge), gamma/beta from uniform global loads
  {
    float o[32]; float sm = 0.f;
    #pragma unroll
    for (int c4 = 0; c4 < 8; ++c4) {
      float4 v4 = *(const float4*)&es[tid*36 + c4*4];
      o[c4*4+0]=v4.x; o[c4*4+1]=v4.y; o[c4*4+2]=v4.z; o[c4*4+3]=v4.w;
      sm += v4.x; sm += v4.y; sm += v4.z; sm += v4.w;
    }
    float mu = sm * (1.f/32.f);
    float sq = 0.f;
    #pragma unroll
    for (int c = 0; c < 32; ++c) { float dd = o[c]-mu; sq += dd*dd; }
    float isd = 1.f / sqrtf(sq*(1.f/32.f) + 1e-4f);
    #pragma unroll
    for (int c4 = 0; c4 < 8; ++c4) {
      float4 g4 = *(const float4*)&elg[c4*4];
      float4 b4 = *(const float4*)&elb[c4*4];
      float4 r4;
      r4.x = valid ? ((o[c4*4+0]-mu)*isd*g4.x + b4.x) : 0.f;
      r4.y = valid ? ((o[c4*4+1]-mu)*isd*g4.y + b4.y) : 0.f;
      r4.z = valid ? ((o[c4*4+2]-mu)*isd*g4.z + b4.z) : 0.f;
      r4.w = valid ? ((o[c4*4+3]-mu)*isd*g4.w + b4.w) : 0.f;
      *(float4*)&es[tid*36 + c4*4] = r4;
    }
  }
  __syncthreads();

  // coalesced ES out (stride 36)
  {
    size_t base32 = OUT_ES + (size_t)blockIdx.x * 256 * 32;
    #pragma unroll
    for (int kk = 0; kk < 8; ++kk) {
      int flat = (kk*256 + tid) * 4;
      int el = flat >> 5, c0 = flat & 31;
      float4 vq = *(const float4*)&es[el*36 + c0];
      *(float4*)&out[base32 + flat] = vq;
    }
  }
  // EV staging in st region (st no longer read); then coalesced float4 out
  st[tid*3 + 0] = valid ? ev0 : 0.f;
  st[tid*3 + 1] = valid ? ev1 : 0.f;
  st[tid*3 + 2] = valid ? ev2 : 0.f;
  __syncthreads();
  if (tid < 192) {
    size_t base3 = OUT_EV + (size_t)blockIdx.x * 768;
    float4 vq = {st[tid*4], st[tid*4+1], st[tid*4+2], st[tid*4+3]};
    *(float4*)&out[base3 + tid*4] = vq;
  }
}

// ---------------- Kernel D4: node LayerNorm + confidence RBF term ----------------
__global__ __launch_bounds__(256) void kln_node(const float* __restrict__ conf,
    const float* __restrict__ cw, const float* __restrict__ cb,
    const float* __restrict__ lg, const float* __restrict__ lb,
    float* __restrict__ out) {
  int n = blockIdx.x, tid = threadIdx.x;
  size_t base = OUT_NS + (size_t)n*NSc;
  float x0 = out[base + tid];
  float x1 = out[base + tid + 256];
  float x2 = out[base + tid + 512];
  float x3 = out[base + tid + 768];
  float sm = x0+x1+x2+x3;
  float sq = x0*x0+x1*x1+x2*x2+x3*x3;
  int lane = tid & 63, wid = tid >> 6;
  #pragma unroll
  for (int off = 32; off > 0; off >>= 1) { sm += __shfl_down(sm, off); sq += __shfl_down(sq, off); }
  __shared__ float rs[4], rq[4];
  if (lane == 0) { rs[wid] = sm; rq[wid] = sq; }
  __syncthreads();
  sm = rs[0]+rs[1]+rs[2]+rs[3];
  sq = rq[0]+rq[1]+rq[2]+rq[3];
  float mu = sm * (1.f/1024.f);
  float var = fmaxf(sq * (1.f/1024.f) - mu*mu, 0.f);
  float isd = 1.f / sqrtf(var + 1e-4f);
  float cf = conf[n];
  float rb[16];
  #pragma unroll
  for (int m = 0; m < 16; ++m) {
    float z = (cf - (float)m*(1.f/15.f)) * 16.f;
    rb[m] = expf(-z*z);
  }
  float xs_[4] = {x0, x1, x2, x3};
  #pragma unroll
  for (int q = 0; q < 4; ++q) {
    int c = tid + q*256;
    float t = cb[c];
    #pragma unroll
    for (int m = 0; m < 16; ++m) t = fmaf(rb[m], cw[m*1024 + c], t);
    out[base + c] = (xs_[q]-mu)*isd*lg[c] + lb[c] + t;
  }
}

extern "C" void kernel_launch(void* const* d_in, const int* in_sizes, int n_in,
                              void* d_out, int out_size, void* d_ws, size_t ws_size,
                              hipStream_t stream) {
  const float* coords         = (const float*)d_in[0];
  const unsigned char* cmask  = (const unsigned char*)d_in[1];
  const int* resid            = (const int*)d_in[2];
  const unsigned char* pmask  = (const unsigned char*)d_in[3];
  const float* conf           = (const float*)d_in[4];
  const float* nwh            = (const float*)d_in[5];
  const float* nww            = (const float*)d_in[6];
  const float* nwb            = (const float*)d_in[7];
  const float* nwv            = (const float*)d_in[8];
  const float* nlg            = (const float*)d_in[9];
  const float* nlb            = (const float*)d_in[10];
  const float* ewh            = (const float*)d_in[11];
  const float* eww            = (const float*)d_in[12];
  const float* ewb            = (const float*)d_in[13];
  const float* ewv            = (const float*)d_in[14];
  const float* elg            = (const float*)d_in[15];
  const float* elb            = (const float*)d_in[16];
  const float* cw             = (const float*)d_in[17];
  const float* cb             = (const float*)d_in[18];
  float* out = (float*)d_out;
  float* ws  = (float*)d_ws;
  float* esbase = out + OUT_ES;                  // ES region scratch (consumed pre-kedge)
  float4* whwv4 = (float4*)esbase;               // 256 float4
  float4* wht4  = whwv4 + 256;                   // 256 float4
  unsigned short* Ahi = (unsigned short*)(esbase + 2048);
  unsigned short* Alo = Ahi + (size_t)Nn * KP;
  unsigned short* BhiT = Alo + (size_t)Nn * KP;
  unsigned short* BloT = BhiT + (size_t)NSc * KP;
  float4* pack  = (float4*)(out + OUT_EV);       // packed Ca+flags (ev region)

  kinit<<<36, 256, 0, stream>>>(cmask, coords, resid, pmask, nwh, nwv, ws, pack, whwv4, wht4);
  knode_geom<<<Nn/64, 64, 0, stream>>>(coords, ws);
  kvnode<<<Nn/4, 256, 0, stream>>>(wht4, whwv4, ws, out);
  ktopk<<<Nn/4, 256, 0, stream>>>(pack, ws);
  kprepA<<<Nn, 64, 0, stream>>>(ws, Ahi, Alo);
  kprepB<<<288, 256, 0, stream>>>(nww, BhiT, BloT);
  kgemm_s<<<(Nn/64)*(NSc/128), 256, 0, stream>>>(Ahi, Alo, BhiT, BloT, nwb, out);
  kedge<<<NEc/256, 256, 0, stream>>>(coords, resid, ewh, eww, ewb, ewv, elg, elb, ws, out);
  kln_node<<<Nn, 256, 0, stream>>>(conf, cw, cb, nlg, nlb, out);
}